// Round 7
// baseline (52.802 us; speedup 1.0000x reference)
//
#include <hip/hip_runtime.h>
#include <math.h>

// SoftHd via bf16 MFMA: A-in-registers, B streamed through LDS, 4 pairs/block.
// v1: (64,128,128) f32, sz1: (64,), v2: (64,128,128) f32, sz2: (64,), out (64,64) f32.
// out[b1,b2] = sum_{j<sz2} min_{i<sz1} dist[i,j] + sum_{i<sz1} min_{j<sz2} dist[i,j]
// dist via gemm identity on bf16-rounded inputs (MFMA 16x16x32_bf16); sqrt is
// monotone -> mins on squared distances, sqrt after reduction; masking folded
// into +INF operands. Block = (b1, 4 consecutive b2): per wave, the A-quadrant
// (64 rows x K=128) lives in 64 VGPRs loaded straight from the quarter-blocked
// global layout; only B panels are staged (two 16 KB LDS half-buffers, one
// barrier per half-phase, STAGE issued before compute).

typedef __attribute__((ext_vector_type(8))) short short8;
typedef __attribute__((ext_vector_type(4))) float f32x4;
typedef unsigned int u32;
typedef unsigned short ushort_t;

static __device__ __forceinline__ ushort_t f32_to_bf16_rne(float f) {
    u32 b = __float_as_uint(f);
    b += 0x7FFFu + ((b >> 16) & 1u);
    return (ushort_t)(b >> 16);
}

// ---------------------------------------------------------------------------
// Pre-kernel: f32 -> bf16 into the quarter-blocked layout + per-row squared
// norms (fp32 of the ROUNDED values).
//   panel byte offset(r, c16) = (c16>>2)*8192 + (r>>3)*512 + (c16&3)*128 + (r&7)*16
// ---------------------------------------------------------------------------
__global__ __launch_bounds__(256) void softhd_pre(
    const float* __restrict__ v1, const float* __restrict__ v2,
    ushort_t* __restrict__ v1b, ushort_t* __restrict__ v2b,
    float* __restrict__ x2g, float* __restrict__ y2g)
{
    int flat = blockIdx.x * 256 + threadIdx.x;
    int c = flat & 15;                 // 16B chunk within row (k-chunk)
    int r = (flat >> 4) & 127;         // row
    int b = (flat >> 11) & 63;         // batch
    int t = flat >> 17;                // tensor select

    const float* src = (t ? v2 : v1) + ((size_t)((b << 7) + r) << 7) + c * 8;
    char* dstp = (char*)((t ? v2b : v1b) + ((size_t)b << 14));

    float4 q0 = *(const float4*)(src);
    float4 q1 = *(const float4*)(src + 4);

    ushort_t h[8];
    h[0] = f32_to_bf16_rne(q0.x); h[1] = f32_to_bf16_rne(q0.y);
    h[2] = f32_to_bf16_rne(q0.z); h[3] = f32_to_bf16_rne(q0.w);
    h[4] = f32_to_bf16_rne(q1.x); h[5] = f32_to_bf16_rne(q1.y);
    h[6] = f32_to_bf16_rne(q1.z); h[7] = f32_to_bf16_rne(q1.w);

    float p = 0.f;
#pragma unroll
    for (int k = 0; k < 8; ++k) {
        float fv = __uint_as_float((u32)h[k] << 16);
        p += fv * fv;
    }

    uint4 w;
    w.x = (u32)h[0] | ((u32)h[1] << 16);
    w.y = (u32)h[2] | ((u32)h[3] << 16);
    w.z = (u32)h[4] | ((u32)h[5] << 16);
    w.w = (u32)h[6] | ((u32)h[7] << 16);

    int off = ((c >> 2) << 13) + ((r >> 3) << 9) + ((c & 3) << 7) + ((r & 7) << 4);
    *(uint4*)(dstp + off) = w;

    p += __shfl_xor(p, 1);
    p += __shfl_xor(p, 2);
    p += __shfl_xor(p, 4);
    p += __shfl_xor(p, 8);
    if (c == 0) (t ? y2g : x2g)[(b << 7) + r] = p;
}

// ---------------------------------------------------------------------------
// Main kernel: 1024 blocks = 64 b1 x 16 groups of 4 b2. 4 waves, 2x2 quadrant
// split per pair (64x64 out per wave).
// ---------------------------------------------------------------------------
__global__ __launch_bounds__(256, 3) void softhd_mfma(
    const ushort_t* __restrict__ v1b, const ushort_t* __restrict__ v2b,
    const float* __restrict__ x2g, const float* __restrict__ y2g,
    const int* __restrict__ sz1, const int* __restrict__ sz2,
    float* __restrict__ out)
{
    __shared__ __align__(16) ushort_t sB[2][8192];  // two 16 KB half-buffers
    __shared__ float sx2[128];
    __shared__ float sy2[4][128];
    __shared__ u32 sbm1[4][128];   // per-b2 min over i, indexed by j
    __shared__ u32 sbm2[4][128];   // per-b2 min over j, indexed by i

    const int tid = threadIdx.x;
    const int lane = tid & 63;
    const int wid = tid >> 6;
    // XCD-bijective swizzle (1024 % 8 == 0).
    const int bid = ((blockIdx.x & 7) << 7) | (blockIdx.x >> 3);
    const int b1 = bid >> 4;
    const int b2base = (bid & 15) << 2;

    // Stage half h of panel (b2base+b2l) into buffer dbuf (16 KB linear copy).
#define STAGE(dbuf, b2l, h)                                                   \
    {                                                                         \
        const char* _g = (const char*)(v2b + ((size_t)(b2base + (b2l)) << 14))\
                         + ((h) << 14);                                       \
        _Pragma("unroll")                                                     \
        for (int e = 0; e < 4; ++e) {                                         \
            int m16 = ((e << 8) + tid) << 4;                                  \
            __builtin_amdgcn_global_load_lds(                                 \
                (const __attribute__((address_space(1))) u32*)(_g + m16),     \
                (__attribute__((address_space(3))) u32*)((char*)&sB[dbuf][0] + m16), \
                16, 0, 0);                                                    \
        }                                                                     \
    }

    STAGE(0, 0, 0);

    const int qr = wid >> 1, qc = wid & 1;
    const int ibase = qr << 6, jbase = qc << 6;
    const int rf = lane & 15, kg = lane >> 4;

    // A-quadrant straight into registers from the quarter-blocked layout:
    // byte(f,q) = q*8192 + ((ibase+f*16+rf)>>3)*512 + kg*128 + (rf&7)*16
    //           = base0 + f*1024 + q*8192
    short8 afr[4][4];
    {
        const char* gA = (const char*)(v1b + ((size_t)b1 << 14));
        const int base0 = (((ibase + rf) >> 3) << 9) + (kg << 7) + ((rf & 7) << 4);
#pragma unroll
        for (int f = 0; f < 4; ++f)
#pragma unroll
            for (int q = 0; q < 4; ++q)
                afr[f][q] = *(const short8*)(gA + base0 + (f << 10) + (q << 13));
    }

    if (tid < 128) sx2[tid] = x2g[(b1 << 7) + tid];
#pragma unroll
    for (int k = 0; k < 2; ++k) {
        ((float*)sy2)[tid + (k << 8)] = y2g[(b2base << 7) + tid + (k << 8)];
        ((u32*)sbm1)[tid + (k << 8)] = 0x7F800000u;   // +inf bits
        ((u32*)sbm2)[tid + (k << 8)] = 0x7F800000u;
    }

    const int n1 = min(max(sz1[b1], 0), 128);
    int n2v[4];
#pragma unroll
    for (int z = 0; z < 4; ++z) n2v[z] = min(max(sz2[b2base + z], 0), 128);

    __syncthreads();   // buf0 + A-regs + LDS init all resident

    const int boff0 = (((jbase + rf) >> 3) << 9) + (kg << 7) + ((rf & 7) << 4);
    const float INF = __builtin_inff();

    f32x4 acc[4][4];

    // 8 phases: phase t computes half (t&1) of pair b2l=(t>>1) from buf (t&1),
    // while staging the next half into the other buffer.
#pragma unroll
    for (int t = 0; t < 8; ++t) {
        const int b2l = t >> 1, h = t & 1, d = t & 1;
        if (t < 7) STAGE(d ^ 1, (t + 1) >> 1, (t + 1) & 1);
        if (h == 0) {
#pragma unroll
            for (int fi = 0; fi < 4; ++fi)
#pragma unroll
                for (int fj = 0; fj < 4; ++fj)
                    acc[fi][fj] = (f32x4){0.f, 0.f, 0.f, 0.f};
        }
#pragma unroll
        for (int qq = 0; qq < 2; ++qq) {
            const int q = h * 2 + qq;
            short8 bfr[4];
#pragma unroll
            for (int fj = 0; fj < 4; ++fj)
                bfr[fj] = *(const short8*)((const char*)&sB[d][0]
                                           + (qq << 13) + (fj << 10) + boff0);
#pragma unroll
            for (int fi = 0; fi < 4; ++fi)
#pragma unroll
                for (int fj = 0; fj < 4; ++fj)
                    acc[fi][fj] = __builtin_amdgcn_mfma_f32_16x16x32_bf16(
                        afr[fi][q], bfr[fj], acc[fi][fj], 0, 0, 0);
        }
        if (h == 1) {
            // ---- epilogue for pair b2l (pure reg/shfl + LDS atomics) ----
            float yje[4];
#pragma unroll
            for (int fj = 0; fj < 4; ++fj) {
                int j = jbase + (fj << 4) + rf;
                yje[fj] = (j < n2v[b2l]) ? sy2[b2l][j] : INF;
            }
            float minj[4] = {INF, INF, INF, INF};
            float mini[16];
#pragma unroll
            for (int z = 0; z < 16; ++z) mini[z] = INF;

#pragma unroll
            for (int fi = 0; fi < 4; ++fi) {
                float4 xs = *(const float4*)&sx2[ibase + (fi << 4) + (kg << 2)];
                float xie[4];
#pragma unroll
                for (int qe = 0; qe < 4; ++qe) {
                    int i = ibase + (fi << 4) + (kg << 2) + qe;
                    xie[qe] = (i < n1) ? ((const float*)&xs)[qe] : INF;
                }
#pragma unroll
                for (int fj = 0; fj < 4; ++fj) {
                    float u0 = fmaf(acc[fi][fj][0], -2.f, xie[0] + yje[fj]);
                    float u1 = fmaf(acc[fi][fj][1], -2.f, xie[1] + yje[fj]);
                    float u2 = fmaf(acc[fi][fj][2], -2.f, xie[2] + yje[fj]);
                    float u3 = fmaf(acc[fi][fj][3], -2.f, xie[3] + yje[fj]);
                    minj[fj] = fminf(fminf(fminf(minj[fj], u0), u1),
                                     fminf(u2, u3));
                    mini[(fi << 2) + 0] = fminf(mini[(fi << 2) + 0], u0);
                    mini[(fi << 2) + 1] = fminf(mini[(fi << 2) + 1], u1);
                    mini[(fi << 2) + 2] = fminf(mini[(fi << 2) + 2], u2);
                    mini[(fi << 2) + 3] = fminf(mini[(fi << 2) + 3], u3);
                }
            }

            // Merge-reduce mini over rf lanes (acc bit k folded with lane bit k).
#pragma unroll
            for (int k = 0; k < 4; ++k) {
                const int dd = 1 << k;
                const bool hi = (lane >> k) & 1;
#pragma unroll
                for (int base = 0; base < 16; base += 2 * (1 << k)) {
                    float pa = fminf(mini[base], __shfl_xor(mini[base], dd));
                    float pb = fminf(mini[base + dd],
                                     __shfl_xor(mini[base + dd], dd));
                    mini[base] = hi ? pb : pa;
                }
            }
            {
                float dmin = __builtin_amdgcn_sqrtf(fmaxf(mini[0], 0.f));
                int i = ibase + ((rf >> 2) << 4) + (kg << 2) + (rf & 3);
                atomicMin(&sbm2[b2l][i], __float_as_uint(dmin));
            }
            // Merge-reduce minj over kg lanes (acc bit k with lane bit 4+k).
#pragma unroll
            for (int k = 0; k < 2; ++k) {
                const int dd = 16 << k;
                const bool hi = (lane >> (4 + k)) & 1;
#pragma unroll
                for (int base = 0; base < 4; base += 2 * (1 << k)) {
                    float pa = fminf(minj[base], __shfl_xor(minj[base], dd));
                    float pb = fminf(minj[base + (1 << k)],
                                     __shfl_xor(minj[base + (1 << k)], dd));
                    minj[base] = hi ? pb : pa;
                }
            }
            {
                float dmin = __builtin_amdgcn_sqrtf(fmaxf(minj[0], 0.f));
                atomicMin(&sbm1[b2l][jbase + lane], __float_as_uint(dmin));
            }
        }
        __syncthreads();
    }
#undef STAGE

    // Final: wave w reduces pair b2l = w.
    {
        const int nn2 = n2v[wid];
        float v = 0.f;
        const int e0 = lane, e1 = lane + 64;
        if (n1 > 0) {
            if (e0 < nn2) v += __uint_as_float(sbm1[wid][e0]);
            if (e1 < nn2) v += __uint_as_float(sbm1[wid][e1]);
        }
        if (nn2 > 0) {
            if (e0 < n1) v += __uint_as_float(sbm2[wid][e0]);
            if (e1 < n1) v += __uint_as_float(sbm2[wid][e1]);
        }
#pragma unroll
        for (int off = 32; off >= 1; off >>= 1) v += __shfl_down(v, off);
        if (lane == 0) out[(b1 << 6) + b2base + wid] = v;
    }
}

extern "C" void kernel_launch(void* const* d_in, const int* in_sizes, int n_in,
                              void* d_out, int out_size, void* d_ws, size_t ws_size,
                              hipStream_t stream) {
    const float* v1  = (const float*)d_in[0];
    const int*   sz1 = (const int*)d_in[1];
    const float* v2  = (const float*)d_in[2];
    const int*   sz2 = (const int*)d_in[3];
    float* out = (float*)d_out;
    (void)in_sizes; (void)n_in; (void)out_size; (void)ws_size;

    char* ws = (char*)d_ws;
    ushort_t* v1b = (ushort_t*)ws;                       // 2 MB
    ushort_t* v2b = (ushort_t*)(ws + (2u << 20));        // 2 MB
    float*    x2g = (float*)(ws + (4u << 20));           // 32 KB
    float*    y2g = x2g + 64 * 128;                      // 32 KB

    softhd_pre<<<dim3(1024), dim3(256), 0, stream>>>(v1, v2, v1b, v2b, x2g, y2g);
    softhd_mfma<<<dim3(1024), dim3(256), 0, stream>>>(v1b, v2b, x2g, y2g,
                                                      sz1, sz2, out);
}

// Round 8
// 36.017 us; speedup vs baseline: 1.4660x; 1.4660x over previous
//
#include <hip/hip_runtime.h>
#include <math.h>

// SoftHd via bf16 MFMA, K-quartered pipeline with COUNTED vmcnt (T4):
// prefetch stays in flight across raw s_barriers; vmcnt never drained to 0
// in the main loop. One block per (b1,b2), 4 waves, 2x2 quadrant split.
// dist via gemm identity on bf16-rounded inputs; sqrt monotone -> mins on
// squared distances, sqrt after reduction; masking folded into +INF operands.
// Quarter-blocked global bf16 layout (pre-kernel):
//   panel byte off(r,c16) = (c16>>2)*8192 + (r>>3)*512 + (c16&3)*128 + (r&7)*16
// -> each K-quarter is one contiguous 8 KB block: linear global_load_lds copy,
//    2-way-aliased (free) ds_read_b128 fragment reads.

typedef __attribute__((ext_vector_type(8))) short short8;
typedef __attribute__((ext_vector_type(4))) float f32x4;
typedef unsigned int u32;
typedef unsigned short ushort_t;

static __device__ __forceinline__ ushort_t f32_to_bf16_rne(float f) {
    u32 b = __float_as_uint(f);
    b += 0x7FFFu + ((b >> 16) & 1u);
    return (ushort_t)(b >> 16);
}

// ---------------------------------------------------------------------------
// Pre-kernel: f32 -> bf16 into quarter-blocked layout + per-row squared norms
// (fp32 of the ROUNDED values).
// ---------------------------------------------------------------------------
__global__ __launch_bounds__(256) void softhd_pre(
    const float* __restrict__ v1, const float* __restrict__ v2,
    ushort_t* __restrict__ v1b, ushort_t* __restrict__ v2b,
    float* __restrict__ x2g, float* __restrict__ y2g)
{
    int flat = blockIdx.x * 256 + threadIdx.x;
    int c = flat & 15;
    int r = (flat >> 4) & 127;
    int b = (flat >> 11) & 63;
    int t = flat >> 17;

    const float* src = (t ? v2 : v1) + ((size_t)((b << 7) + r) << 7) + c * 8;
    char* dstp = (char*)((t ? v2b : v1b) + ((size_t)b << 14));

    float4 q0 = *(const float4*)(src);
    float4 q1 = *(const float4*)(src + 4);

    ushort_t h[8];
    h[0] = f32_to_bf16_rne(q0.x); h[1] = f32_to_bf16_rne(q0.y);
    h[2] = f32_to_bf16_rne(q0.z); h[3] = f32_to_bf16_rne(q0.w);
    h[4] = f32_to_bf16_rne(q1.x); h[5] = f32_to_bf16_rne(q1.y);
    h[6] = f32_to_bf16_rne(q1.z); h[7] = f32_to_bf16_rne(q1.w);

    float p = 0.f;
#pragma unroll
    for (int k = 0; k < 8; ++k) {
        float fv = __uint_as_float((u32)h[k] << 16);
        p += fv * fv;
    }

    uint4 w;
    w.x = (u32)h[0] | ((u32)h[1] << 16);
    w.y = (u32)h[2] | ((u32)h[3] << 16);
    w.z = (u32)h[4] | ((u32)h[5] << 16);
    w.w = (u32)h[6] | ((u32)h[7] << 16);

    int off = ((c >> 2) << 13) + ((r >> 3) << 9) + ((c & 3) << 7) + ((r & 7) << 4);
    *(uint4*)(dstp + off) = w;

    p += __shfl_xor(p, 1);
    p += __shfl_xor(p, 2);
    p += __shfl_xor(p, 4);
    p += __shfl_xor(p, 8);
    if (c == 0) (t ? y2g : x2g)[(b << 7) + r] = p;
}

// ---------------------------------------------------------------------------
// Main kernel.
// ---------------------------------------------------------------------------
__global__ __launch_bounds__(256, 4) void softhd_mfma(
    const ushort_t* __restrict__ v1b, const ushort_t* __restrict__ v2b,
    const float* __restrict__ x2g, const float* __restrict__ y2g,
    const int* __restrict__ sz1, const int* __restrict__ sz2,
    float* __restrict__ out)
{
    __shared__ __align__(16) ushort_t sb[2][2][4096];  // [buf][panel][8 KB]
    __shared__ float sx2[128], sy2[128];
    __shared__ u32 sbm1[128], sbm2[128];
    __shared__ float swsum[4];

    const int tid = threadIdx.x;
    const int lane = tid & 63;
    const int wid = tid >> 6;
    // XCD-bijective swizzle (4096 % 8 == 0).
    const int bid = ((blockIdx.x & 7) << 9) | (blockIdx.x >> 3);
    const int b1 = bid >> 6, b2 = bid & 63;

    const char* gp0 = (const char*)(v1b + ((size_t)b1 << 14));
    const char* gp1 = (const char*)(v2b + ((size_t)b2 << 14));

    const int n1 = min(max(sz1[b1], 0), 128);
    const int n2 = min(max(sz2[b2], 0), 128);

    // Norm loads + LDS init FIRST, fully retired before any STAGE issues, so
    // the compiler's dependent vmcnt drain can't catch staging loads.
    if (tid < 128) {
        sx2[tid] = x2g[(b1 << 7) + tid];
        sbm1[tid] = 0x7F800000u;            // +inf bits
    } else {
        sy2[tid - 128] = y2g[(b2 << 7) + (tid - 128)];
        sbm2[tid - 128] = 0x7F800000u;
    }
    asm volatile("" ::: "memory");          // pin order: init before staging

#define STAGE(d, q)                                                          \
    {                                                                        \
        _Pragma("unroll")                                                    \
        for (int e = 0; e < 2; ++e) {                                        \
            int m16 = ((e << 8) + tid) << 4;                                 \
            __builtin_amdgcn_global_load_lds(                                \
                (const __attribute__((address_space(1))) u32*)(gp0 + ((q) << 13) + m16), \
                (__attribute__((address_space(3))) u32*)((char*)&sb[d][0][0] + m16),     \
                16, 0, 0);                                                   \
            __builtin_amdgcn_global_load_lds(                                \
                (const __attribute__((address_space(1))) u32*)(gp1 + ((q) << 13) + m16), \
                (__attribute__((address_space(3))) u32*)((char*)&sb[d][1][0] + m16),     \
                16, 0, 0);                                                   \
        }                                                                    \
    }
// Counted wait: own older loads done, newer prefetch stays in flight.
#define WAITV4()  asm volatile("s_waitcnt vmcnt(4)" ::: "memory")
#define WAITV0()  asm volatile("s_waitcnt vmcnt(0)" ::: "memory")
#define BAR()     asm volatile("s_barrier" ::: "memory")

    STAGE(0, 0);                             // 4 loads/thread
    STAGE(1, 1);                             // +4 -> 8 in flight

    const int qr = wid >> 1, qc = wid & 1;
    const int ibase = qr << 6, jbase = qc << 6;
    const int rf = lane & 15, kg = lane >> 4;

    // frag elem offsets within an 8 KB quarter: (row>>3)*256 + kg*64 + (row&7)*8
    int aoff[4], boff[4];
#pragma unroll
    for (int f = 0; f < 4; ++f) {
        int ra = ibase + (f << 4) + rf;
        int rb = jbase + (f << 4) + rf;
        aoff[f] = ((ra >> 3) << 8) + (kg << 6) + ((ra & 7) << 3);
        boff[f] = ((rb >> 3) << 8) + (kg << 6) + ((rb & 7) << 3);
    }

    f32x4 acc[4][4];
#pragma unroll
    for (int fi = 0; fi < 4; ++fi)
#pragma unroll
        for (int fj = 0; fj < 4; ++fj)
            acc[fi][fj] = (f32x4){0.f, 0.f, 0.f, 0.f};

#define COMPUTE(d)                                                           \
    {                                                                        \
        short8 a[4], b[4];                                                   \
        _Pragma("unroll")                                                    \
        for (int f = 0; f < 4; ++f) {                                        \
            a[f] = *(const short8*)(&sb[d][0][0] + aoff[f]);                 \
            b[f] = *(const short8*)(&sb[d][1][0] + boff[f]);                 \
        }                                                                    \
        _Pragma("unroll")                                                    \
        for (int fi = 0; fi < 4; ++fi)                                       \
            _Pragma("unroll")                                                \
            for (int fj = 0; fj < 4; ++fj)                                   \
                acc[fi][fj] = __builtin_amdgcn_mfma_f32_16x16x32_bf16(       \
                    a[fi], b[fj], acc[fi][fj], 0, 0, 0);                     \
    }

    // q0: wait own loads (q1 stays in flight), compute, then refill buf0.
    WAITV4(); BAR();
    COMPUTE(0);
    BAR(); STAGE(0, 2);
    // q1
    WAITV4(); BAR();
    COMPUTE(1);
    BAR(); STAGE(1, 3);
    // q2
    WAITV4(); BAR();
    COMPUTE(0);
    BAR();
    // q3 (last: drain)
    WAITV0(); BAR();
    COMPUTE(1);

#undef COMPUTE
#undef STAGE
#undef WAITV4
#undef WAITV0
#undef BAR

    const float INF = __builtin_inff();

    // Operand-folded masking: invalid rows/cols contribute +INF.
    float xie[16], yje[4];
#pragma unroll
    for (int t = 0; t < 16; ++t) {
        int i = ibase + ((t >> 2) << 4) + (kg << 2) + (t & 3);
        xie[t] = (i < n1) ? sx2[i] : INF;
    }
#pragma unroll
    for (int fj = 0; fj < 4; ++fj) {
        int j = jbase + (fj << 4) + rf;
        yje[fj] = (j < n2) ? sy2[j] : INF;
    }

    float minj[4], mini[16];
#pragma unroll
    for (int fj = 0; fj < 4; ++fj) minj[fj] = INF;
#pragma unroll
    for (int t = 0; t < 16; ++t) mini[t] = INF;

#pragma unroll
    for (int fi = 0; fi < 4; ++fi) {
        float u[4][4];
#pragma unroll
        for (int fj = 0; fj < 4; ++fj)
#pragma unroll
            for (int q = 0; q < 4; ++q)
                u[fj][q] = fmaf(acc[fi][fj][q], -2.f, xie[fi * 4 + q] + yje[fj]);
#pragma unroll
        for (int fj = 0; fj < 4; ++fj) {
            minj[fj] = fminf(fminf(minj[fj], u[fj][0]), u[fj][1]);
            minj[fj] = fminf(fminf(minj[fj], u[fj][2]), u[fj][3]);
        }
#pragma unroll
        for (int q = 0; q < 4; ++q) {
            float mt = mini[fi * 4 + q];
            mt = fminf(fminf(mt, u[0][q]), u[1][q]);
            mt = fminf(fminf(mt, u[2][q]), u[3][q]);
            mini[fi * 4 + q] = mt;
        }
    }

    // Merge-reduce mini over rf lanes (acc bit k folded with lane bit k).
#pragma unroll
    for (int k = 0; k < 4; ++k) {
        const int d = 1 << k;
        const bool hi = (lane >> k) & 1;
#pragma unroll
        for (int base = 0; base < 16; base += 2 * (1 << k)) {
            float pa = fminf(mini[base], __shfl_xor(mini[base], d));
            float pb = fminf(mini[base + d], __shfl_xor(mini[base + d], d));
            mini[base] = hi ? pb : pa;
        }
    }
    {
        float dmin = __builtin_amdgcn_sqrtf(fmaxf(mini[0], 0.f));
        int i = ibase + ((rf >> 2) << 4) + (kg << 2) + (rf & 3);
        atomicMin(&sbm2[i], __float_as_uint(dmin));
    }

    // Merge-reduce minj over kg lanes (acc bit k with lane bit 4+k).
#pragma unroll
    for (int k = 0; k < 2; ++k) {
        const int d = 16 << k;
        const bool hi = (lane >> (4 + k)) & 1;
#pragma unroll
        for (int base = 0; base < 4; base += 2 * (1 << k)) {
            float pa = fminf(minj[base], __shfl_xor(minj[base], d));
            float pb = fminf(minj[base + (1 << k)],
                             __shfl_xor(minj[base + (1 << k)], d));
            minj[base] = hi ? pb : pa;
        }
    }
    {
        float dmin = __builtin_amdgcn_sqrtf(fmaxf(minj[0], 0.f));
        atomicMin(&sbm1[jbase + lane], __float_as_uint(dmin));
    }
    __syncthreads();

    float v = 0.f;
    if (tid < 128) {
        if (n1 > 0 && tid < n2) v += __uint_as_float(sbm1[tid]);
        if (n2 > 0 && tid < n1) v += __uint_as_float(sbm2[tid]);
    }
#pragma unroll
    for (int off = 32; off >= 1; off >>= 1) v += __shfl_down(v, off);
    if (lane == 0) swsum[wid] = v;
    __syncthreads();
    if (tid == 0) out[bid] = swsum[0] + swsum[1] + swsum[2] + swsum[3];
}

extern "C" void kernel_launch(void* const* d_in, const int* in_sizes, int n_in,
                              void* d_out, int out_size, void* d_ws, size_t ws_size,
                              hipStream_t stream) {
    const float* v1  = (const float*)d_in[0];
    const int*   sz1 = (const int*)d_in[1];
    const float* v2  = (const float*)d_in[2];
    const int*   sz2 = (const int*)d_in[3];
    float* out = (float*)d_out;
    (void)in_sizes; (void)n_in; (void)out_size; (void)ws_size;

    char* ws = (char*)d_ws;
    ushort_t* v1b = (ushort_t*)ws;                       // 2 MB
    ushort_t* v2b = (ushort_t*)(ws + (2u << 20));        // 2 MB
    float*    x2g = (float*)(ws + (4u << 20));           // 32 KB
    float*    y2g = x2g + 64 * 128;                      // 32 KB

    softhd_pre<<<dim3(1024), dim3(256), 0, stream>>>(v1, v2, v1b, v2b, x2g, y2g);
    softhd_mfma<<<dim3(4096), dim3(256), 0, stream>>>(v1b, v2b, x2g, y2g,
                                                      sz1, sz2, out);
}